// Round 5
// baseline (254.259 us; speedup 1.0000x reference)
//
#include <hip/hip_runtime.h>

// VQ-VAE quantization forward for MI355X (gfx950).
// outputs (concat in d_out, fp32): quantized_ [16*4096*256], commitment_loss [1], perplexity [1]
//
// v6: barrier-light, L2-direct B, 2-way code split with STAGGERED shared-row A-loads.
//   - 512 blocks x 512 threads (8 waves). Block owns 128 rows. Wave (rp,h): rows rp*32..+31,
//     code half h (h=0: codes 0..255, h=1: 256..511). 4096 waves total = 16 waves/CU.
//   - h0 waves load x (HBM); one barrier; h1 waves reload the SAME rows (L2/L3-hot, no 2nd
//     HBM fetch) while h0 waves already scan codes. No other main-loop barriers: B-fragments
//     read straight from L2 (bswz 256 KB, XCD-hot) into registers, double-buffered.
//   - Output is exactly the gathered raw codebook row (x + sg(q-x) -> q; (q+q)/2 = q).
//     Loss via ||x||^2 + cA[c] + cB[c]*score, no x re-read. FULL 128-row epilogue (v4/v5
//     only wrote 1/4 of each row -- fixed).
//   - Score path bit-identical to v2/v3 (same fragments, K-order, -bias init, strict->
//     ascending argmax; half-combine ties pick the lower index).

typedef _Float16 half8_t __attribute__((ext_vector_type(8)));
typedef _Float16 half4_t __attribute__((ext_vector_type(4)));
typedef float f32x4 __attribute__((ext_vector_type(4)));

static constexpr int kRows = 65536;   // N*T
static constexpr int kD = 256;
static constexpr int kM = 512;
static constexpr int kBM = 128;       // rows per block

// ---------------- prep: normalize codebook -> fp16 in MFMA B-fragment order, bias, cA/cB, zero hist/loss
// swz layout (halves): [group g=c>>4][ko=k>>5][lane = qd*16 + (c&15)][j = k&7], qd=(k>>3)&3.
// A wave's contiguous 1 KB read at (g*4096 + ko*512 + lane*8) halves yields exactly the
// mfma_f32_16x16x32_f16 B-fragment: lane holds B[k=ko*32+(lane>>4)*8+j][n=lane&15].
__global__ void vq_prep(const float* __restrict__ emb, _Float16* __restrict__ swz,
                        float* __restrict__ bias, float2* __restrict__ cab,
                        unsigned int* __restrict__ hist, float* __restrict__ loss) {
    const int j = blockIdx.x;       // code row, 512 blocks
    const int lane = threadIdx.x;   // 64 threads = 1 wave
    float4 v = ((const float4*)(emb + j * kD))[lane];
    float ss = v.x * v.x + v.y * v.y + v.z * v.z + v.w * v.w;
    #pragma unroll
    for (int off = 32; off > 0; off >>= 1) ss += __shfl_xor(ss, off);
    const float s = sqrtf(ss) + 1e-4f;      // ||emb_raw|| + 1e-4
    const float scale = 1.0f / s;
    if (lane == 0) {
        bias[j] = 0.5f * ss * scale * scale;            // 0.5*||e_norm||^2
        cab[j] = make_float2(ss * (1.0f - scale),       // cA = q2*(1-1/s)
                             -2.0f * s);                // cB
    }
    half4_t h;
    h[0] = (_Float16)(v.x * scale);
    h[1] = (_Float16)(v.y * scale);
    h[2] = (_Float16)(v.z * scale);
    h[3] = (_Float16)(v.w * scale);
    const int k0 = lane * 4;
    const int ko = k0 >> 5;
    const int qd = (k0 >> 3) & 3;
    const int jj = k0 & 7;
    const int off_h = (j >> 4) * 4096 + ko * 512 + (qd * 16 + (j & 15)) * 8 + jj;
    *(half4_t*)(swz + off_h) = h;
    if (j == 0) {
        for (int b = lane; b < kM; b += 64) hist[b] = 0u;
        if (lane == 0) loss[0] = 0.0f;
    }
}

// ---------------- main: 32 rows/wave, code-split halves, L2-direct B, staggered A ----------------
__global__ __launch_bounds__(512, 4) void vq_main(
    const float* __restrict__ x, const float* __restrict__ emb,
    const _Float16* __restrict__ bswz, const float* __restrict__ bias,
    const float2* __restrict__ cab, unsigned int* __restrict__ hist,
    float* __restrict__ loss_accum, float* __restrict__ out) {
    __shared__ float lbv[kBM][2];           // per-row best score, per code-half
    __shared__ int   lbi[kBM][2];           // per-row best index, per code-half
    __shared__ float lssq[kBM];             // per-row ||x||^2
    __shared__ int   lidx[kBM];             // per-row winner
    __shared__ unsigned int lhist[kM];      // 2048 B
    __shared__ float lred[2];

    const int t = threadIdx.x;              // 0..511, 8 waves
    const int wave = t >> 6;
    const int lane = t & 63;
    const int ln = lane & 15;
    const int qd = lane >> 4;
    const int rp = wave & 3;                // row-pair 0..3
    const int h = wave >> 2;                // code half 0..1
    const int row0 = blockIdx.x * kBM;
    const int r0 = row0 + rp * 32;          // wave's 32 rows

    lhist[t] = 0u;

    // B prologue: first tile of this half (L2) + its bias
    half8_t ba[8], bb[8];
    const int t0 = h * 16;                  // first code-tile index for this half
    {
        const _Float16* b0 = bswz + (size_t)t0 * 4096 + lane * 8;
        #pragma unroll
        for (int ko = 0; ko < 8; ++ko) ba[ko] = *(const half8_t*)(b0 + ko * 512);
    }
    float bias_c = bias[t0 * 16 + ln];

    // A fragments (two 16-row sets); STAGGERED: h0 loads from HBM, h1 re-reads L2/L3-hot.
    half8_t a0[8], a1[8];
    float ssq0 = 0.0f, ssq1 = 0.0f;
    auto loadA = [&]() {
        const float* xr0 = x + (size_t)(r0 + ln) * kD + qd * 8;
        const float* xr1 = xr0 + 16 * kD;
        #pragma unroll
        for (int ko = 0; ko < 8; ++ko) {
            const float4 u0 = *(const float4*)(xr0 + ko * 32);
            const float4 u1 = *(const float4*)(xr0 + ko * 32 + 4);
            const float4 w0 = *(const float4*)(xr1 + ko * 32);
            const float4 w1 = *(const float4*)(xr1 + ko * 32 + 4);
            half8_t h0, h1;
            h0[0] = (_Float16)u0.x; h0[1] = (_Float16)u0.y;
            h0[2] = (_Float16)u0.z; h0[3] = (_Float16)u0.w;
            h0[4] = (_Float16)u1.x; h0[5] = (_Float16)u1.y;
            h0[6] = (_Float16)u1.z; h0[7] = (_Float16)u1.w;
            h1[0] = (_Float16)w0.x; h1[1] = (_Float16)w0.y;
            h1[2] = (_Float16)w0.z; h1[3] = (_Float16)w0.w;
            h1[4] = (_Float16)w1.x; h1[5] = (_Float16)w1.y;
            h1[6] = (_Float16)w1.z; h1[7] = (_Float16)w1.w;
            a0[ko] = h0; a1[ko] = h1;
            ssq0 += u0.x*u0.x + u0.y*u0.y + u0.z*u0.z + u0.w*u0.w
                  + u1.x*u1.x + u1.y*u1.y + u1.z*u1.z + u1.w*u1.w;
            ssq1 += w0.x*w0.x + w0.y*w0.y + w0.z*w0.z + w0.w*w0.w
                  + w1.x*w1.x + w1.y*w1.y + w1.z*w1.z + w1.w*w1.w;
        }
    };
    if (h == 0) loadA();
    __syncthreads();        // h0's x lines now in L2/L3; h1 reads them cheaply while h0 scans
    if (h == 1) loadA();

    float bv0[4] = {-1e30f, -1e30f, -1e30f, -1e30f};
    float bv1[4] = {-1e30f, -1e30f, -1e30f, -1e30f};
    int bi0[4] = {0, 0, 0, 0};
    int bi1[4] = {0, 0, 0, 0};

    // score = x.e_norm - 0.5*||e_norm||^2; single f32 acc chain per row-set (bit-matches v2/v3)
    auto compute = [&](int gt, const half8_t (&b)[8], float bg) {
        f32x4 acc0 = {-bg, -bg, -bg, -bg};
        f32x4 acc1 = {-bg, -bg, -bg, -bg};
        #pragma unroll
        for (int ko = 0; ko < 8; ++ko) {
            acc0 = __builtin_amdgcn_mfma_f32_16x16x32_f16(a0[ko], b[ko], acc0, 0, 0, 0);
            acc1 = __builtin_amdgcn_mfma_f32_16x16x32_f16(a1[ko], b[ko], acc1, 0, 0, 0);
        }
        const int c = gt * 16 + ln;
        #pragma unroll
        for (int r = 0; r < 4; ++r) {       // D[m][n]: n=ln, m=qd*4+r; ascending c -> strict >
            if (acc0[r] > bv0[r]) { bv0[r] = acc0[r]; bi0[r] = c; }
            if (acc1[r] > bv1[r]) { bv1[r] = acc1[r]; bi1[r] = c; }
        }
    };

    // scan this half's 16 tiles, double-buffered from L2 (no barriers)
    #pragma unroll 1
    for (int g = 0; g < 16; g += 2) {
        {   // prefetch tile t0+g+1 -> bb
            const _Float16* bn = bswz + (size_t)(t0 + g + 1) * 4096 + lane * 8;
            #pragma unroll
            for (int ko = 0; ko < 8; ++ko) bb[ko] = *(const half8_t*)(bn + ko * 512);
        }
        const float bias_n = bias[(t0 + g + 1) * 16 + ln];
        compute(t0 + g, ba, bias_c);
        if (g + 2 < 16) {   // prefetch tile t0+g+2 -> ba
            const _Float16* bn = bswz + (size_t)(t0 + g + 2) * 4096 + lane * 8;
            #pragma unroll
            for (int ko = 0; ko < 8; ++ko) ba[ko] = *(const half8_t*)(bn + ko * 512);
            bias_c = bias[(t0 + g + 2) * 16 + ln];
        }
        compute(t0 + g + 1, bb, bias_n);
    }

    // per-row argmax across the 16 lanes of each quad (different code subsets within half)
    #pragma unroll
    for (int r = 0; r < 4; ++r) {
        #pragma unroll
        for (int off = 1; off < 16; off <<= 1) {
            const float ov0 = __shfl_xor(bv0[r], off);
            const int   oi0 = __shfl_xor(bi0[r], off);
            if (ov0 > bv0[r] || (ov0 == bv0[r] && oi0 < bi0[r])) { bv0[r] = ov0; bi0[r] = oi0; }
            const float ov1 = __shfl_xor(bv1[r], off);
            const int   oi1 = __shfl_xor(bi1[r], off);
            if (ov1 > bv1[r] || (ov1 == bv1[r] && oi1 < bi1[r])) { bv1[r] = ov1; bi1[r] = oi1; }
        }
    }
    // broadcast row ssq (row m's ssq lives in lanes with ln == m&15)
    float ssA[4], ssB[4];
    #pragma unroll
    for (int r = 0; r < 4; ++r) {
        ssq0 += 0.0f; ssq1 += 0.0f;
    }
    {
        float s0 = ssq0, s1 = ssq1;
        s0 += __shfl_xor(s0, 16); s0 += __shfl_xor(s0, 32);
        s1 += __shfl_xor(s1, 16); s1 += __shfl_xor(s1, 32);
        #pragma unroll
        for (int r = 0; r < 4; ++r) {
            ssA[r] = __shfl(s0, qd * 4 + r);
            ssB[r] = __shfl(s1, qd * 4 + r);
        }
    }
    if (ln == 0) {
        #pragma unroll
        for (int r = 0; r < 4; ++r) {
            const int m = rp * 32 + qd * 4 + r;
            lbv[m][h] = bv0[r];      lbi[m][h] = bi0[r];
            lbv[m + 16][h] = bv1[r]; lbi[m + 16][h] = bi1[r];
            if (h == 0) { lssq[m] = ssA[r]; lssq[m + 16] = ssB[r]; }
        }
    }
    __syncthreads();

    // combine halves per row; LDS hist; loss term (no x re-read)
    float term = 0.0f;
    if (t < kBM) {
        const float v0 = lbv[t][0], v1 = lbv[t][1];
        const int i0 = lbi[t][0], i1 = lbi[t][1];
        const bool take1 = (v1 > v0);       // tie -> i0 (always the lower index)
        const int win = take1 ? i1 : i0;
        const float sc = take1 ? v1 : v0;
        lidx[t] = win;
        atomicAdd(&lhist[win], 1u);
        const float2 cc = cab[win];
        term = lssq[t] + cc.x + cc.y * sc;
    }
    if (wave < 2) {
        #pragma unroll
        for (int off = 32; off > 0; off >>= 1) term += __shfl_xor(term, off);
        if (lane == 0) lred[wave] = term;
    }
    __syncthreads();
    if (t == 0) atomicAdd(loss_accum, lred[0] + lred[1]);

    // epilogue: FULL write of quantized_ = gathered raw codebook rows.
    // Wave w writes rows w*16..w*16+15; each row = 64 lanes x float4 = 1 KB coalesced.
    {
        float* og = out + (size_t)(row0 + wave * 16) * kD;
        #pragma unroll 4
        for (int i = 0; i < 16; ++i) {
            const int idx = lidx[wave * 16 + i];
            const float4 q = *(const float4*)(emb + (size_t)idx * kD + lane * 4);
            *(float4*)(og + i * kD + lane * 4) = q;
        }
    }

    // flush histogram (skip zero bins); lhist final since the barrier above
    const unsigned int hv = lhist[t];
    if (hv) atomicAdd(&hist[t], hv);
}

// ---------------- final: scalars ----------------
__global__ void vq_final(const unsigned int* __restrict__ hist,
                         const float* __restrict__ loss_accum,
                         float* __restrict__ out) {
    const int t = threadIdx.x;  // 256 threads
    __shared__ float sr[4];
    float s = 0.0f;
    for (int b = t; b < kM; b += 256) {
        const float p = (float)hist[b] * (1.0f / 65536.0f);
        s += p * logf(p + 1e-10f);
    }
    #pragma unroll
    for (int off = 32; off > 0; off >>= 1) s += __shfl_xor(s, off);
    if ((t & 63) == 0) sr[t >> 6] = s;
    __syncthreads();
    if (t == 0) {
        const float tot = sr[0] + sr[1] + sr[2] + sr[3];
        out[16777217] = expf(-tot);                           // perplexity
        out[16777216] = loss_accum[0] * (1.0f / 16777216.0f); // commitment loss
    }
}

extern "C" void kernel_launch(void* const* d_in, const int* in_sizes, int n_in,
                              void* d_out, int out_size, void* d_ws, size_t ws_size,
                              hipStream_t stream) {
    const float* x = (const float*)d_in[0];     // (16,4096,256) fp32
    const float* emb = (const float*)d_in[1];   // (512,256) fp32
    char* ws = (char*)d_ws;
    _Float16* bswz = (_Float16*)ws;                            // 262144 B
    float* bias = (float*)(ws + 262144);                       // 2048 B
    unsigned int* hist = (unsigned int*)(ws + 264192);         // 2048 B
    float* loss = (float*)(ws + 266240);                       // 16 B
    float2* cab = (float2*)(ws + 266256);                      // 4096 B
    float* out = (float*)d_out;

    vq_prep<<<kM, 64, 0, stream>>>(emb, bswz, bias, cab, hist, loss);
    vq_main<<<kRows / kBM, 512, 0, stream>>>(x, emb, bswz, bias, cab, hist, loss, out);
    vq_final<<<1, 256, 0, stream>>>(hist, loss, out);
}

// Round 6
// 174.530 us; speedup vs baseline: 1.4568x; 1.4568x over previous
//
#include <hip/hip_runtime.h>

// VQ-VAE quantization forward for MI355X (gfx950).
// outputs (concat in d_out, fp32): quantized_ [16*4096*256], commitment_loss [1], perplexity [1]
//
// v7 = v6's plan in v3's proven register configuration.
//   - TOOLCHAIN NOTE: __launch_bounds__ 2nd arg empirically acts as min BLOCKS/CU here:
//     (512,4) clamped VGPR to 64 and spilled ~100 regs/thread in v4-v6 (WRITE 371 MB vs 67
//     ideal = scratch traffic). (256,2) -> cap 256, v3 measured VGPR=92, clean counters.
//   - 1024 blocks x 256 threads (4 waves). Block owns 64 rows. Wave (rp,h): rows rp*32..+31,
//     code half h (h=0: codes 0..255, h=1: 256..511). 4096 waves = 16 waves/CU (2x v3).
//   - h0 waves load x (HBM); one barrier; h1 waves reload the SAME rows cache-hot while h0
//     already scans. Main loop barrier-free: B-fragments read straight from L2 (bswz 256 KB,
//     XCD-hot) into registers, double-buffered, 128 KB per wave.
//   - Output is exactly the gathered raw codebook row (x + sg(q-x) -> q; (q+q)/2 = q).
//     Loss via ||x||^2 + cA[c] + cB[c]*score, no x re-read.
//   - Score path bit-identical to v2/v3/v6 (same fragments, K-order, -bias init, ascending
//     strict-> argmax; half-combine ties pick the lower index). absmax must stay 0.2202148.

typedef _Float16 half8_t __attribute__((ext_vector_type(8)));
typedef _Float16 half4_t __attribute__((ext_vector_type(4)));
typedef float f32x4 __attribute__((ext_vector_type(4)));

static constexpr int kRows = 65536;   // N*T
static constexpr int kD = 256;
static constexpr int kM = 512;
static constexpr int kBM = 64;        // rows per block

// ---------------- prep: normalize codebook -> fp16 in MFMA B-fragment order, bias, cA/cB, zero hist/loss
// swz layout (halves): [group g=c>>4][ko=k>>5][lane = qd*16 + (c&15)][j = k&7], qd=(k>>3)&3.
// A wave's contiguous 1 KB read at (g*4096 + ko*512 + lane*8) halves yields exactly the
// mfma_f32_16x16x32_f16 B-fragment: lane holds B[k=ko*32+(lane>>4)*8+j][n=lane&15].
__global__ void vq_prep(const float* __restrict__ emb, _Float16* __restrict__ swz,
                        float* __restrict__ bias, float2* __restrict__ cab,
                        unsigned int* __restrict__ hist, float* __restrict__ loss) {
    const int j = blockIdx.x;       // code row, 512 blocks
    const int lane = threadIdx.x;   // 64 threads = 1 wave
    float4 v = ((const float4*)(emb + j * kD))[lane];
    float ss = v.x * v.x + v.y * v.y + v.z * v.z + v.w * v.w;
    #pragma unroll
    for (int off = 32; off > 0; off >>= 1) ss += __shfl_xor(ss, off);
    const float s = sqrtf(ss) + 1e-4f;      // ||emb_raw|| + 1e-4
    const float scale = 1.0f / s;
    if (lane == 0) {
        bias[j] = 0.5f * ss * scale * scale;            // 0.5*||e_norm||^2
        cab[j] = make_float2(ss * (1.0f - scale),       // cA = q2*(1-1/s)
                             -2.0f * s);                // cB
    }
    half4_t h;
    h[0] = (_Float16)(v.x * scale);
    h[1] = (_Float16)(v.y * scale);
    h[2] = (_Float16)(v.z * scale);
    h[3] = (_Float16)(v.w * scale);
    const int k0 = lane * 4;
    const int ko = k0 >> 5;
    const int qd = (k0 >> 3) & 3;
    const int jj = k0 & 7;
    const int off_h = (j >> 4) * 4096 + ko * 512 + (qd * 16 + (j & 15)) * 8 + jj;
    *(half4_t*)(swz + off_h) = h;
    if (j == 0) {
        for (int b = lane; b < kM; b += 64) hist[b] = 0u;
        if (lane == 0) loss[0] = 0.0f;
    }
}

// ---------------- main: 32 rows/wave, 2-way code split, L2-direct B, staggered A ----------------
__global__ __launch_bounds__(256, 2) void vq_main(
    const float* __restrict__ x, const float* __restrict__ emb,
    const _Float16* __restrict__ bswz, const float* __restrict__ bias,
    const float2* __restrict__ cab, unsigned int* __restrict__ hist,
    float* __restrict__ loss_accum, float* __restrict__ out) {
    __shared__ float lbv[kBM][2];           // per-row best score, per code-half
    __shared__ int   lbi[kBM][2];           // per-row best index, per code-half
    __shared__ float lssq[kBM];             // per-row ||x||^2
    __shared__ int   lidx[kBM];             // per-row winner
    __shared__ unsigned int lhist[kM];      // 2048 B

    const int t = threadIdx.x;              // 0..255, 4 waves
    const int wave = t >> 6;
    const int lane = t & 63;
    const int ln = lane & 15;
    const int qd = lane >> 4;
    const int rp = wave & 1;                // row-pair 0..1
    const int h = wave >> 1;                // code half 0..1
    const int row0 = blockIdx.x * kBM;
    const int r0 = row0 + rp * 32;          // wave's 32 rows

    lhist[t] = 0u;
    lhist[t + 256] = 0u;

    // B prologue: first tile of this half (L2-direct) + its bias
    half8_t ba[8], bb[8];
    const int t0 = h * 16;                  // first code-tile index for this half
    {
        const _Float16* b0 = bswz + (size_t)t0 * 4096 + lane * 8;
        #pragma unroll
        for (int ko = 0; ko < 8; ++ko) ba[ko] = *(const half8_t*)(b0 + ko * 512);
    }
    float bias_c = bias[t0 * 16 + ln];

    // A fragments (two 16-row sets); STAGGERED: h0 loads from HBM, h1 re-reads cache-hot.
    half8_t a0[8], a1[8];
    float ssq0 = 0.0f, ssq1 = 0.0f;
    auto loadA = [&]() {
        const float* xr0 = x + (size_t)(r0 + ln) * kD + qd * 8;
        const float* xr1 = xr0 + 16 * kD;
        #pragma unroll
        for (int ko = 0; ko < 8; ++ko) {
            const float4 u0 = *(const float4*)(xr0 + ko * 32);
            const float4 u1 = *(const float4*)(xr0 + ko * 32 + 4);
            const float4 w0 = *(const float4*)(xr1 + ko * 32);
            const float4 w1 = *(const float4*)(xr1 + ko * 32 + 4);
            half8_t h0, h1;
            h0[0] = (_Float16)u0.x; h0[1] = (_Float16)u0.y;
            h0[2] = (_Float16)u0.z; h0[3] = (_Float16)u0.w;
            h0[4] = (_Float16)u1.x; h0[5] = (_Float16)u1.y;
            h0[6] = (_Float16)u1.z; h0[7] = (_Float16)u1.w;
            h1[0] = (_Float16)w0.x; h1[1] = (_Float16)w0.y;
            h1[2] = (_Float16)w0.z; h1[3] = (_Float16)w0.w;
            h1[4] = (_Float16)w1.x; h1[5] = (_Float16)w1.y;
            h1[6] = (_Float16)w1.z; h1[7] = (_Float16)w1.w;
            a0[ko] = h0; a1[ko] = h1;
            ssq0 += u0.x*u0.x + u0.y*u0.y + u0.z*u0.z + u0.w*u0.w
                  + u1.x*u1.x + u1.y*u1.y + u1.z*u1.z + u1.w*u1.w;
            ssq1 += w0.x*w0.x + w0.y*w0.y + w0.z*w0.z + w0.w*w0.w
                  + w1.x*w1.x + w1.y*w1.y + w1.z*w1.z + w1.w*w1.w;
        }
    };
    if (h == 0) loadA();
    __syncthreads();        // h0's x lines now cached; also covers lhist init
    if (h == 1) loadA();

    float bv0[4] = {-1e30f, -1e30f, -1e30f, -1e30f};
    float bv1[4] = {-1e30f, -1e30f, -1e30f, -1e30f};
    int bi0[4] = {0, 0, 0, 0};
    int bi1[4] = {0, 0, 0, 0};

    // score = x.e_norm - 0.5*||e_norm||^2; single f32 acc chain per row-set (bit-matches v2/v3)
    auto compute = [&](int gt, const half8_t (&b)[8], float bg) {
        f32x4 acc0 = {-bg, -bg, -bg, -bg};
        f32x4 acc1 = {-bg, -bg, -bg, -bg};
        #pragma unroll
        for (int ko = 0; ko < 8; ++ko) {
            acc0 = __builtin_amdgcn_mfma_f32_16x16x32_f16(a0[ko], b[ko], acc0, 0, 0, 0);
            acc1 = __builtin_amdgcn_mfma_f32_16x16x32_f16(a1[ko], b[ko], acc1, 0, 0, 0);
        }
        const int c = gt * 16 + ln;
        #pragma unroll
        for (int r = 0; r < 4; ++r) {       // D[m][n]: n=ln, m=qd*4+r; ascending c -> strict >
            if (acc0[r] > bv0[r]) { bv0[r] = acc0[r]; bi0[r] = c; }
            if (acc1[r] > bv1[r]) { bv1[r] = acc1[r]; bi1[r] = c; }
        }
    };

    // scan this half's 16 tiles, double-buffered from L2 (no barriers)
    #pragma unroll 1
    for (int g = 0; g < 16; g += 2) {
        {   // prefetch tile t0+g+1 -> bb
            const _Float16* bn = bswz + (size_t)(t0 + g + 1) * 4096 + lane * 8;
            #pragma unroll
            for (int ko = 0; ko < 8; ++ko) bb[ko] = *(const half8_t*)(bn + ko * 512);
        }
        const float bias_n = bias[(t0 + g + 1) * 16 + ln];
        compute(t0 + g, ba, bias_c);
        if (g + 2 < 16) {   // prefetch tile t0+g+2 -> ba
            const _Float16* bn = bswz + (size_t)(t0 + g + 2) * 4096 + lane * 8;
            #pragma unroll
            for (int ko = 0; ko < 8; ++ko) ba[ko] = *(const half8_t*)(bn + ko * 512);
            bias_c = bias[(t0 + g + 2) * 16 + ln];
        }
        compute(t0 + g + 1, bb, bias_n);
    }

    // per-row argmax across the 16 lanes of each quad (different code subsets within half)
    #pragma unroll
    for (int r = 0; r < 4; ++r) {
        #pragma unroll
        for (int off = 1; off < 16; off <<= 1) {
            const float ov0 = __shfl_xor(bv0[r], off);
            const int   oi0 = __shfl_xor(bi0[r], off);
            if (ov0 > bv0[r] || (ov0 == bv0[r] && oi0 < bi0[r])) { bv0[r] = ov0; bi0[r] = oi0; }
            const float ov1 = __shfl_xor(bv1[r], off);
            const int   oi1 = __shfl_xor(bi1[r], off);
            if (ov1 > bv1[r] || (ov1 == bv1[r] && oi1 < bi1[r])) { bv1[r] = ov1; bi1[r] = oi1; }
        }
    }
    // row ssq: sum the 4 qd-lanes sharing ln, then broadcast (row m's ssq at ln==m&15)
    float ssA[4], ssB[4];
    {
        float s0 = ssq0, s1 = ssq1;
        s0 += __shfl_xor(s0, 16); s0 += __shfl_xor(s0, 32);
        s1 += __shfl_xor(s1, 16); s1 += __shfl_xor(s1, 32);
        #pragma unroll
        for (int r = 0; r < 4; ++r) {
            ssA[r] = __shfl(s0, qd * 4 + r);
            ssB[r] = __shfl(s1, qd * 4 + r);
        }
    }
    if (ln == 0) {
        #pragma unroll
        for (int r = 0; r < 4; ++r) {
            const int m = rp * 32 + qd * 4 + r;
            lbv[m][h] = bv0[r];      lbi[m][h] = bi0[r];
            lbv[m + 16][h] = bv1[r]; lbi[m + 16][h] = bi1[r];
            if (h == 0) { lssq[m] = ssA[r]; lssq[m + 16] = ssB[r]; }
        }
    }
    __syncthreads();

    // combine halves per row (wave 0 = threads 0..63 covers all 64 rows); LDS hist; loss term
    float term = 0.0f;
    if (t < kBM) {
        const float v0 = lbv[t][0], v1 = lbv[t][1];
        const int i0 = lbi[t][0], i1 = lbi[t][1];
        const bool take1 = (v1 > v0);       // tie -> i0 (always the lower index)
        const int win = take1 ? i1 : i0;
        const float sc = take1 ? v1 : v0;
        lidx[t] = win;
        atomicAdd(&lhist[win], 1u);
        const float2 cc = cab[win];
        term = lssq[t] + cc.x + cc.y * sc;
    }
    if (wave == 0) {
        #pragma unroll
        for (int off = 32; off > 0; off >>= 1) term += __shfl_xor(term, off);
        if (lane == 0) atomicAdd(loss_accum, term);
    }
    __syncthreads();                        // lidx visible to all waves

    // epilogue: write quantized_ = gathered raw codebook rows.
    // Wave w writes rows w*16..w*16+15; each row = 64 lanes x float4 = 1 KB coalesced.
    {
        float* og = out + (size_t)(row0 + wave * 16) * kD;
        #pragma unroll 4
        for (int i = 0; i < 16; ++i) {
            const int idx = lidx[wave * 16 + i];
            const float4 q = *(const float4*)(emb + (size_t)idx * kD + lane * 4);
            *(float4*)(og + i * kD + lane * 4) = q;
        }
    }

    // flush histogram (skip zero bins); lhist final since the barrier above
    const unsigned int h0v = lhist[t];
    if (h0v) atomicAdd(&hist[t], h0v);
    const unsigned int h1v = lhist[t + 256];
    if (h1v) atomicAdd(&hist[t + 256], h1v);
}

// ---------------- final: scalars ----------------
__global__ void vq_final(const unsigned int* __restrict__ hist,
                         const float* __restrict__ loss_accum,
                         float* __restrict__ out) {
    const int t = threadIdx.x;  // 256 threads
    __shared__ float sr[4];
    float s = 0.0f;
    for (int b = t; b < kM; b += 256) {
        const float p = (float)hist[b] * (1.0f / 65536.0f);
        s += p * logf(p + 1e-10f);
    }
    #pragma unroll
    for (int off = 32; off > 0; off >>= 1) s += __shfl_xor(s, off);
    if ((t & 63) == 0) sr[t >> 6] = s;
    __syncthreads();
    if (t == 0) {
        const float tot = sr[0] + sr[1] + sr[2] + sr[3];
        out[16777217] = expf(-tot);                           // perplexity
        out[16777216] = loss_accum[0] * (1.0f / 16777216.0f); // commitment loss
    }
}

extern "C" void kernel_launch(void* const* d_in, const int* in_sizes, int n_in,
                              void* d_out, int out_size, void* d_ws, size_t ws_size,
                              hipStream_t stream) {
    const float* x = (const float*)d_in[0];     // (16,4096,256) fp32
    const float* emb = (const float*)d_in[1];   // (512,256) fp32
    char* ws = (char*)d_ws;
    _Float16* bswz = (_Float16*)ws;                            // 262144 B
    float* bias = (float*)(ws + 262144);                       // 2048 B
    unsigned int* hist = (unsigned int*)(ws + 264192);         // 2048 B
    float* loss = (float*)(ws + 266240);                       // 16 B
    float2* cab = (float2*)(ws + 266256);                      // 4096 B
    float* out = (float*)d_out;

    vq_prep<<<kM, 64, 0, stream>>>(emb, bswz, bias, cab, hist, loss);
    vq_main<<<kRows / kBM, 256, 0, stream>>>(x, emb, bswz, bias, cab, hist, loss, out);
    vq_final<<<1, 256, 0, stream>>>(hist, loss, out);
}